// Round 4
// baseline (111.987 us; speedup 1.0000x reference)
//
#include <hip/hip_runtime.h>
#include <hip/hip_bf16.h>

// CapsuleLayer on MI355X — R8: ROLLED main loop (I$-thrash theory). R4/R6/R7
// all sat at ~42-47us regardless of B-staging schedule with a fully-unrolled
// 25-step kk loop (~25KB+ body). This round: kh/kw as REAL loops (body ~1KB),
// Bs buffer rotation via offset var, wave-uniform branches for counted waits.
// All else unchanged from R7: direct-u A staging, dense swizzled As, triple-
// buffered Bs via global_load_lds + counted vmcnt(4), setprio around MFMA.
// b stays 0 (faithful torch bug) => one dense conv 64ci->128co, 5x5, pad 2;
// v = squash_z1(p/(8*cnt)); out [N, t1, z1, H, W].

#define CO 128

typedef __attribute__((ext_vector_type(8))) short bf16x8;
typedef __attribute__((ext_vector_type(4))) float f32x4;

__device__ __forceinline__ void glds16(const void* g, void* l) {
    __builtin_amdgcn_global_load_lds((const __attribute__((address_space(1))) void*)g,
                                     (__attribute__((address_space(3))) void*)l, 16, 0, 0);
}

// ---- W fp32 [t0][co][z0][5][5] -> Wr2 bf16 [kk][co][chunk^(co&7)][8]
__global__ __launch_bounds__(256) void k_reorder(const float* __restrict__ Wsrc,
                                                 ushort* __restrict__ Wr2) {
    int idx = blockIdx.x * 256 + threadIdx.x;   // 800 blocks = 25*128*64 exact
    int ci = idx & 63;
    int r  = idx >> 6;
    int co = r & 127;
    int kk = r >> 7;
    int t0 = ci >> 4, z0 = ci & 15;
    __hip_bfloat16 bb = __float2bfloat16(Wsrc[((t0 * CO + co) * 16 + z0) * 25 + kk]);
    int chunk = (ci >> 3) ^ (co & 7);           // XOR swizzle baked into Wr2
    Wr2[((kk * CO + co) << 6) + (chunk << 3) + (ci & 7)] = *(ushort*)&bb;
}

// ---- main: grid 512 = 4(n) x 16(by: 8 rows) x 8(bx: 16 cols), 256 thr = 4 waves
// wave: wm4 = (wid>>1)*4 -> image rows [h0+wm4, +4); wn64 = (wid&1)*64 -> co.
// As dense [p][64], chunk XOR p&7 (write+read involution). Bs: 3 buffers
// (flat 3*8192 ushorts), counted vmcnt(4), raw s_barrier.
__global__ __launch_bounds__(256) void k_caps(const float* __restrict__ u,
                                              const ushort* __restrict__ Wr2,
                                              float* __restrict__ out) {
    __shared__ ushort As[240 * 64];      // 30720 B, dense swizzled
    __shared__ ushort Bs[3 * 128 * 64];  // 49152 B, triple-buffered (flat)

    int tid = threadIdx.x;
    int bid = blockIdx.x;
    int bx = bid & 7, by = (bid >> 3) & 15, n = bid >> 7;
    int h0 = by * 8, w0 = bx * 16;

    int lane = tid & 63, wid = tid >> 6;
    int wm4  = (wid >> 1) * 4;
    int wn64 = (wid & 1) * 64;
    int q = lane >> 4, m16 = lane & 15;
    int m7 = m16 & 7;

    auto stageB = [&](int kk2, int bufOfs) {
#pragma unroll
        for (int j = 0; j < 4; ++j) {
            int i = (j * 256 + wid * 64) * 8;   // wave-uniform LDS base; lane adds 16B
            glds16(Wr2 + (size_t)kk2 * 8192 + i + lane * 8, &Bs[bufOfs + i]);
        }
    };

    // B0 prefetch first — flies under the A staging
    stageB(0, 0);

    // ---- A staging directly from u: thread = pixel p (<240), 8 octet phases,
    // 8 ci-strided scalar loads (coalesced across lanes along w), cvt+pack.
    {
        int p = tid;
        int rr = p / 20;
        int cc = p - rr * 20;
        int hh = h0 + rr - 2, ww = w0 + cc - 2;
        bool inb = (p < 240) & ((unsigned)hh < 128u) & ((unsigned)ww < 128u);
        const float* up = u + (size_t)n * (64 * 128 * 128) + (size_t)hh * 128 + ww;
        int key = (p & 7) << 3;
#pragma unroll
        for (int c8 = 0; c8 < 8; ++c8) {
            bf16x8 vv = {};
            if (inb) {
#pragma unroll
                for (int j = 0; j < 8; ++j) {
                    __hip_bfloat16 bb =
                        __float2bfloat16(up[(size_t)(c8 * 8 + j) * 16384]);
                    vv[j] = *(ushort*)&bb;
                }
            }
            if (p < 240)
                *(bf16x8*)&As[(p << 6) + ((c8 << 3) ^ key)] = vv;
        }
    }
    __syncthreads();                 // full drain: As + B0 landed
    stageB(1, 8192);                 // B1 in flight, depth 2 from here on

    int aP0  = wm4 * 20 + m16;       // lane pixel base
    int bRow = (wn64 + m16) << 6;
    int bsw0 = (q ^ m7) << 3;        // ks=0 B chunk swizzle (lane-const)
    int bsw1 = ((4 + q) ^ m7) << 3;  // ks=1

    f32x4 acc[4][4] = {};

    int bcur = 0;                    // LDS offset of buffer kk%3
    int kk = 0;
#pragma clang loop unroll(disable)
    for (int kh = 0; kh < 5; ++kh) {
#pragma clang loop unroll(disable)
        for (int kw = 0; kw < 5; ++kw) {
            if (kk < 23) {
                int bnxt = bcur + 16384;         // buffer (kk+2)%3
                if (bnxt >= 24576) bnxt -= 24576;
                stageB(kk + 2, bnxt);
            }
            int p0 = aP0 + kh * 20 + kw;
            __builtin_amdgcn_s_setprio(1);
#pragma unroll
            for (int ks = 0; ks < 2; ++ks) {
                int bsw = ks ? bsw1 : bsw0;
                bf16x8 a[4], bb[4];
#pragma unroll
                for (int mi = 0; mi < 4; ++mi) {
                    int p = p0 + mi * 20;
                    int asw = (((ks << 2) + q) ^ (p & 7)) << 3;
                    a[mi] = *(const bf16x8*)&As[(p << 6) + asw];
                }
#pragma unroll
                for (int ni = 0; ni < 4; ++ni)
                    bb[ni] = *(const bf16x8*)&Bs[bcur + bRow + ni * 1024 + bsw];
#pragma unroll
                for (int mi = 0; mi < 4; ++mi)
#pragma unroll
                    for (int ni = 0; ni < 4; ++ni)
                        acc[mi][ni] = __builtin_amdgcn_mfma_f32_16x16x32_bf16(
                            a[mi], bb[ni], acc[mi][ni], 0, 0, 0);
            }
            __builtin_amdgcn_s_setprio(0);
            if (kk < 23) {
                // kk+1's 4 glds retired; kk+2's 4 stay IN FLIGHT across barrier
                asm volatile("s_waitcnt vmcnt(4)" ::: "memory");
                asm volatile("s_barrier" ::: "memory");
            } else if (kk == 23) {
                asm volatile("s_waitcnt vmcnt(0)" ::: "memory");
                asm volatile("s_barrier" ::: "memory");
            }
            bcur += 8192;
            if (bcur >= 24576) bcur -= 24576;
            ++kk;
        }
    }

    // epilogue (R3-proven): scale 1/(8*cnt), squash over z1 (m16 lanes), store
    // D layout: row(m = image col) = q*4+reg, col(n = co) = m16
#pragma unroll
    for (int mi = 0; mi < 4; ++mi) {
        int h = h0 + wm4 + mi;
        int hlo = h - 2; if (hlo < 0) hlo = 0;
        int hhi = h + 2; if (hhi > 127) hhi = 127;
        float cnth = (float)(hhi - hlo + 1);
#pragma unroll
        for (int ni = 0; ni < 4; ++ni) {
            f32x4 cv = acc[mi][ni];
            float ov[4];
#pragma unroll
            for (int reg = 0; reg < 4; ++reg) {
                int w = w0 + q * 4 + reg;
                int wlo = w - 2; if (wlo < 0) wlo = 0;
                int whi = w + 2; if (whi > 127) whi = 127;
                float s = 1.f / (8.f * cnth * (float)(whi - wlo + 1));
                float pv = cv[reg] * s;
                float n2 = pv * pv;
                n2 += __shfl_xor(n2, 1);
                n2 += __shfl_xor(n2, 2);
                n2 += __shfl_xor(n2, 4);
                n2 += __shfl_xor(n2, 8);
                float fac = n2 / ((1.f + n2) * sqrtf(n2 + 1e-9f));
                ov[reg] = pv * fac;
            }
            int co = wn64 + ni * 16 + m16;
            *(float4*)(out + (((size_t)(n * CO + co)) << 14) + h * 128 + w0 + q * 4) =
                make_float4(ov[0], ov[1], ov[2], ov[3]);
        }
    }
}

extern "C" void kernel_launch(void* const* d_in, const int* in_sizes, int n_in,
                              void* d_out, int out_size, void* d_ws, size_t ws_size,
                              hipStream_t stream) {
    const float* u    = (const float*)d_in[0];
    const float* Wsrc = (const float*)d_in[1];
    float* out = (float*)d_out;
    ushort* Wr2 = (ushort*)d_ws;                       // 409600 B

    k_reorder<<<800, 256, 0, stream>>>(Wsrc, Wr2);
    k_caps<<<512, 256, 0, stream>>>(u, Wr2, out);
}

// Round 5
// 111.960 us; speedup vs baseline: 1.0002x; 1.0002x over previous
//
#include <hip/hip_runtime.h>
#include <hip/hip_bf16.h>

// CapsuleLayer on MI355X — R9: OCCUPANCY via ks-split. R4-R8 all ran 8 waves/CU
// (2 waves/SIMD) in barrier lockstep and all landed 43-50us with pipes at
// 20-37% — latency-bound, not traffic-bound (LDS floor ~16us). This round:
// each wave computes HALF the ci reduction (ks = wid&1) -> 4096 waves total,
// 16 waves/CU = 4 waves/SIMD. Partial accs summed through LDS (stride-68
// padded, conflict-free) at the end. Per-kk per-wave: 4 A + 4 B ds_reads +
// 16 MFMA. Triple-buffered B via global_load_lds + counted vmcnt(2) kept.
// b stays 0 (faithful torch bug) => one dense conv 64ci->128co, 5x5, pad 2;
// v = squash_z1(p/(8*cnt)); out [N, t1, z1, H, W].

#define CO 128

typedef __attribute__((ext_vector_type(8))) short bf16x8;
typedef __attribute__((ext_vector_type(4))) float f32x4;

__device__ __forceinline__ void glds16(const void* g, void* l) {
    __builtin_amdgcn_global_load_lds((const __attribute__((address_space(1))) void*)g,
                                     (__attribute__((address_space(3))) void*)l, 16, 0, 0);
}

// ---- W fp32 [t0][co][z0][5][5] -> Wr2 bf16 [kk][co][chunk^(co&7)][8]
__global__ __launch_bounds__(256) void k_reorder(const float* __restrict__ Wsrc,
                                                 ushort* __restrict__ Wr2) {
    int idx = blockIdx.x * 256 + threadIdx.x;   // 800 blocks = 25*128*64 exact
    int ci = idx & 63;
    int r  = idx >> 6;
    int co = r & 127;
    int kk = r >> 7;
    int t0 = ci >> 4, z0 = ci & 15;
    __hip_bfloat16 bb = __float2bfloat16(Wsrc[((t0 * CO + co) * 16 + z0) * 25 + kk]);
    int chunk = (ci >> 3) ^ (co & 7);           // XOR swizzle baked into Wr2
    Wr2[((kk * CO + co) << 6) + (chunk << 3) + (ci & 7)] = *(ushort*)&bb;
}

// ---- main: grid 512 = 4(n) x 16(by: 8 rows) x 8(bx: 16 cols)
// 512 thr = 8 waves = (rg:2 rows-groups) x (cg:2 co-groups) x (ks:2 ci-halves)
// As dense [p][64], chunk XOR p&7. Bs: 3 buffers, counted vmcnt(2), s_barrier.
// End: ks=1 waves write acc to LDS (stride-68 f32, conflict-free), ks=0 add
// and run squash epilogue.
__global__ __launch_bounds__(512) void k_caps(const float* __restrict__ u,
                                              const ushort* __restrict__ Wr2,
                                              float* __restrict__ out) {
    __shared__ ushort SH[39936];         // 79872 B: As 15360 | Bs 3*8192
    ushort* As = SH;
    ushort* Bs = SH + 15360;

    int tid = threadIdx.x;
    int bid = blockIdx.x;
    int bx = bid & 7, by = (bid >> 3) & 15, n = bid >> 7;
    int h0 = by * 8, w0 = bx * 16;

    int lane = tid & 63, wid = tid >> 6;
    int rg = wid >> 2;                   // row group (0..1)
    int cg = (wid >> 1) & 1;             // co group
    int ks = wid & 1;                    // ci half
    int wm4  = rg * 4;
    int wn64 = cg * 64;
    int q = lane >> 4, m16 = lane & 15;
    int m7 = m16 & 7;
    int ksq = ks * 4 + q;                // chunk index 0..7

    auto stageB = [&](int kk2, int bufOfs) {
#pragma unroll
        for (int j = 0; j < 2; ++j) {
            int seg = j * 8 + wid;       // 16 segments of 512 ushorts
            glds16(Wr2 + (size_t)kk2 * 8192 + seg * 512 + lane * 8,
                   &Bs[bufOfs + seg * 512]);
        }
    };

    // B0 prefetch first — flies under the A staging
    stageB(0, 0);

    // ---- A staging directly from u: threads 0..479, 2 threads per pixel,
    // each stages 4 octets (32 ci-strided scalar loads, coalesced along w).
    if (tid < 480) {
        int p = tid >> 1;
        int half = tid & 1;
        int rr = p / 20;
        int cc = p - rr * 20;
        int hh = h0 + rr - 2, ww = w0 + cc - 2;
        bool inb = ((unsigned)hh < 128u) & ((unsigned)ww < 128u);
        const float* up = u + (size_t)n * (64 * 128 * 128) + (size_t)hh * 128 + ww;
        int key = (p & 7) << 3;
#pragma unroll
        for (int c8 = half * 4; c8 < half * 4 + 4; ++c8) {
            bf16x8 vv = {};
            if (inb) {
#pragma unroll
                for (int j = 0; j < 8; ++j) {
                    __hip_bfloat16 bb =
                        __float2bfloat16(up[(size_t)(c8 * 8 + j) * 16384]);
                    vv[j] = *(ushort*)&bb;
                }
            }
            *(bf16x8*)&As[(p << 6) + ((c8 << 3) ^ key)] = vv;
        }
    }
    __syncthreads();                 // full drain: As + B0 landed
    stageB(1, 8192);                 // B1 in flight, depth 2 from here on

    int aP0  = wm4 * 20 + m16;       // lane pixel base
    int bRow = (wn64 + m16) << 6;
    int bsw  = (ksq ^ m7) << 3;      // B chunk swizzle (lane-const)

    f32x4 acc[4][4] = {};

    int bcur = 0;                    // LDS offset (ushorts) of buffer kk%3
    int kk = 0;
#pragma clang loop unroll(disable)
    for (int kh = 0; kh < 5; ++kh) {
#pragma clang loop unroll(disable)
        for (int kw = 0; kw < 5; ++kw) {
            if (kk < 23) {
                int bnxt = bcur + 16384;         // buffer (kk+2)%3
                if (bnxt >= 24576) bnxt -= 24576;
                stageB(kk + 2, bnxt);
            }
            int p0 = aP0 + kh * 20 + kw;
            __builtin_amdgcn_s_setprio(1);
            bf16x8 a[4], bb[4];
#pragma unroll
            for (int mi = 0; mi < 4; ++mi) {
                int p = p0 + mi * 20;
                int asw = (ksq ^ (p & 7)) << 3;
                a[mi] = *(const bf16x8*)&As[(p << 6) + asw];
            }
#pragma unroll
            for (int ni = 0; ni < 4; ++ni)
                bb[ni] = *(const bf16x8*)&Bs[bcur + bRow + ni * 1024 + bsw];
#pragma unroll
            for (int mi = 0; mi < 4; ++mi)
#pragma unroll
                for (int ni = 0; ni < 4; ++ni)
                    acc[mi][ni] = __builtin_amdgcn_mfma_f32_16x16x32_bf16(
                        a[mi], bb[ni], acc[mi][ni], 0, 0, 0);
            __builtin_amdgcn_s_setprio(0);
            if (kk < 23) {
                // kk+1's 2 glds retired; kk+2's 2 stay IN FLIGHT across barrier
                asm volatile("s_waitcnt vmcnt(2)" ::: "memory");
                asm volatile("s_barrier" ::: "memory");
            } else if (kk == 23) {
                asm volatile("s_waitcnt vmcnt(0)" ::: "memory");
                asm volatile("s_barrier" ::: "memory");
            }
            bcur += 8192;
            if (bcur >= 24576) bcur -= 24576;
            ++kk;
        }
    }

    // ---- ks-reduction: ks=1 waves write partial acc to LDS, ks=0 add.
    // Layout: R[(wv*64+lane)*68 + j*4], wv = rg*2+cg. 68-f32 stride ->
    // per-store banks 4*(lane+j)%32: 8 accesses/bank = b128 floor.
    __syncthreads();                 // all Bs/As reads done before overwrite
    float* R = (float*)SH;
    int rbase = ((rg * 2 + cg) * 64 + lane) * 68;
    if (ks == 1) {
#pragma unroll
        for (int mi = 0; mi < 4; ++mi)
#pragma unroll
            for (int ni = 0; ni < 4; ++ni)
                *(f32x4*)&R[rbase + (mi * 4 + ni) * 4] = acc[mi][ni];
    }
    __syncthreads();
    if (ks == 1) return;
#pragma unroll
    for (int mi = 0; mi < 4; ++mi)
#pragma unroll
        for (int ni = 0; ni < 4; ++ni) {
            f32x4 pv = *(f32x4*)&R[rbase + (mi * 4 + ni) * 4];
            acc[mi][ni] += pv;
        }

    // epilogue (R3-proven): scale 1/(8*cnt), squash over z1 (m16 lanes), store
    // D layout: row(m = image col) = q*4+reg, col(n = co) = m16
#pragma unroll
    for (int mi = 0; mi < 4; ++mi) {
        int h = h0 + wm4 + mi;
        int hlo = h - 2; if (hlo < 0) hlo = 0;
        int hhi = h + 2; if (hhi > 127) hhi = 127;
        float cnth = (float)(hhi - hlo + 1);
#pragma unroll
        for (int ni = 0; ni < 4; ++ni) {
            f32x4 cv = acc[mi][ni];
            float ov[4];
#pragma unroll
            for (int reg = 0; reg < 4; ++reg) {
                int w = w0 + q * 4 + reg;
                int wlo = w - 2; if (wlo < 0) wlo = 0;
                int whi = w + 2; if (whi > 127) whi = 127;
                float s = 1.f / (8.f * cnth * (float)(whi - wlo + 1));
                float pv = cv[reg] * s;
                float n2 = pv * pv;
                n2 += __shfl_xor(n2, 1);
                n2 += __shfl_xor(n2, 2);
                n2 += __shfl_xor(n2, 4);
                n2 += __shfl_xor(n2, 8);
                float fac = n2 / ((1.f + n2) * sqrtf(n2 + 1e-9f));
                ov[reg] = pv * fac;
            }
            int co = wn64 + ni * 16 + m16;
            *(float4*)(out + (((size_t)(n * CO + co)) << 14) + h * 128 + w0 + q * 4) =
                make_float4(ov[0], ov[1], ov[2], ov[3]);
        }
    }
}

extern "C" void kernel_launch(void* const* d_in, const int* in_sizes, int n_in,
                              void* d_out, int out_size, void* d_ws, size_t ws_size,
                              hipStream_t stream) {
    const float* u    = (const float*)d_in[0];
    const float* Wsrc = (const float*)d_in[1];
    float* out = (float*)d_out;
    ushort* Wr2 = (ushort*)d_ws;                       // 409600 B

    k_reorder<<<800, 256, 0, stream>>>(Wsrc, Wr2);
    k_caps<<<512, 512, 0, stream>>>(u, Wr2, out);
}